// Round 10
// baseline (214.128 us; speedup 1.0000x reference)
//
#include <hip/hip_runtime.h>
#include <hip/hip_bf16.h>
#include <math.h>

// Problem constants
#define B_   16
#define D_   512
#define T_   2048
#define K_   8
#define C_   1024
#define CH_  64
#define NEL_ (B_ * D_ * T_)        // 16777216
#define QOFF 16777216              // out: [quantized | commit | ppl[8]]

// ws layout
#define WS_HCN   0                          // float[K*C]   32 KB (0.5*||c||^2)
#define WS_CNT   32768                      // int[K*C]     32 KB
#define WS_SSE   65536                      // double       8 B
#define WS_CBS   66048                      // swizzled bf16 (hi only) image, 8192 rows * 128 B = 1 MB
// image: row r (= k*1024+c) at WS_CBS + r*128; 16B group s (s=0..7, ch 8s..8s+7,
// negated bf16) stored at ((s ^ (r & 7)) * 16).

typedef __attribute__((ext_vector_type(8))) short   short8;
typedef __attribute__((ext_vector_type(8))) __bf16  bf16x8;
typedef __attribute__((ext_vector_type(4))) float   f32x4;
typedef __attribute__((ext_vector_type(4))) int     i32x4;

__device__ __forceinline__ unsigned short f2bf_rne(float f) {
    unsigned u = __builtin_bit_cast(unsigned, f);
    u = u + 0x7FFFu + ((u >> 16) & 1u);
    return (unsigned short)(u >> 16);
}

__device__ __forceinline__ void gload_lds16(const void* gsrc, void* ldst) {
    __builtin_amdgcn_global_load_lds(
        (const __attribute__((address_space(1))) unsigned int*)gsrc,
        (__attribute__((address_space(3))) unsigned int*)ldst,
        16, 0, 0);
}

// ---------------------------------------------------------------------------
// Prep (R0/R2-proven): swizzled bf16 (hi-only) image of (-c) + 0.5*||c||^2,
// plus counts/sse zero-init. One thread per 16B group. 65536 threads.
// ---------------------------------------------------------------------------
__global__ void vq_prep(const float* __restrict__ cb,
                        unsigned char* __restrict__ cbS,
                        float* __restrict__ hcn,
                        int* __restrict__ counts,
                        double* __restrict__ sse) {
    int g   = blockIdx.x * 256 + threadIdx.x;
    if (g < K_ * C_) counts[g] = 0;
    if (g == 0) *sse = 0.0;

    int row = g >> 3;
    int s8  = g & 7;
    const float* src = cb + (size_t)row * CH_;

    short8 val;
#pragma unroll
    for (int j = 0; j < 8; ++j)
        val[j] = (short)f2bf_rne(-src[s8 * 8 + j]);
    *(short8*)(cbS + (size_t)row * 128 + ((s8 ^ (row & 7)) * 16)) = val;

    if (s8 == 0) {
        float s = 0.f;
#pragma unroll 8
        for (int ch = 0; ch < CH_; ++ch) {
            float v = src[ch];
            s = fmaf(v, v, s);
        }
        hcn[row] = 0.5f * s;
    }
}

// ---------------------------------------------------------------------------
// Main — barrier-free full-image sweep.
// R9 post-mortem: 8 per-chunk barrier drains left ~60% of wall time with no
// pipe issuing (dur 108, MFMA 13 + VALU 32 µs). This kernel stages the WHOLE
// 128 KB k-image once and sweeps all 1024 codes with ZERO main-loop barriers.
// R8 re-cluster: packed-fminf argmin explains ALL five prior failures
// (incl. R8 at proven-small LDS); large LDS was a confound. Precedent for
// this launch config: learn_hip m201 8-phase GEMM = static 128 KiB LDS +
// 512 threads on gfx950, verified. Tracker here is R9's slim EXPLICIT
// compare-select verbatim (no packed-fminf; absmax must reproduce
// 0.6113281 bit-for-bit — j = sub gives the identical lexicographic order).
//
// Block = 512 threads (8 waves), wave owns 64 t = 4 t-tiles (R9 shape).
// Grid = 512 = B*K*4 t-quarters; 1 block/CU (2 rounds).
// LDS = 131072 B static, all image; hcn from global (R2-proven broadcast);
// idxS aliases the image after a barrier. 3 barriers total per block.
// ---------------------------------------------------------------------------
#define IMG_BYTES 131072

__global__ __launch_bounds__(512, 1) void vq_main(
    const float* __restrict__ x,
    const float* __restrict__ cb,
    const unsigned char* __restrict__ cbS,
    const float* __restrict__ hcn,
    float* __restrict__ out,
    int* __restrict__ counts,
    double* __restrict__ sse)
{
    __shared__ __align__(16) unsigned char lds[IMG_BYTES];
    int* idxS = (int*)lds;              // alias; valid after post-sweep barrier

    const int tid  = threadIdx.x;
    const int lane = tid & 63;
    const int wave = tid >> 6;          // 0..7
    const int ln   = lane & 15;
    const int q    = lane >> 4;
    const int q4   = q * 4;

    const int bid = blockIdx.x;
    const int tq  = bid & 3;            // quarter of T
    const int k   = (bid >> 2) & 7;
    const int b   = bid >> 5;
    const int t0b = tq * 512;           // block's t base (512 t)
    const int tw  = t0b + wave * 64;    // wave's t base  (64 t)

    const unsigned char* cbS_k = cbS + (size_t)k * C_ * 128;
    const float*         hcn_k = hcn + k * C_;

    // ---- Stage the whole image (128 KB): 16 x 16 B per thread, async.
    // Per issue, wave w writes contiguous 1 KB at (w*1024 + i*8192):
    // wave-uniform base + lane*16 — matches gload_lds lane mapping.
    {
        const unsigned char* src = cbS_k + tid * 16;
        unsigned char*       dst = lds   + tid * 16;
#pragma unroll
        for (int i = 0; i < 16; ++i)
            gload_lds16(src + i * 8192, dst + i * 8192);
    }

    // ---- x fragments (queries) + ||x||^2 per query (R9 verbatim) ----
    // Overlaps the in-flight image staging.
    short8 bh[4][2];    // [tt][kstep]
    float  xn[4];       // ||x_t||^2 for t = tw + tt*16 + ln (all lanes)
#pragma unroll
    for (int tt = 0; tt < 4; ++tt) {
        int t = tw + tt * 16 + ln;
        float pn = 0.f;
#pragma unroll
        for (int ks = 0; ks < 2; ++ks) {
            const float* xp = x + ((size_t)(b * D_ + k * CH_ + ks * 32 + q * 8)) * T_ + t;
            short8 sh;
#pragma unroll
            for (int j = 0; j < 8; ++j) {
                float v = xp[(size_t)j * T_];
                pn = fmaf(v, v, pn);
                sh[j] = (short)f2bf_rne(v);
            }
            bh[tt][ks] = sh;
        }
        pn += __shfl_xor(pn, 16);       // sum the 4 q-lane partials
        pn += __shfl_xor(pn, 32);
        xn[tt] = pn;
    }

    __syncthreads();   // drains image loads; NO further barriers in the sweep

    // ---- Barrier-free sweep over all 1024 codes ----
    // Slot (tt, r) at sub: code = sub*16 + q4 + r, sub in [0,64).
    // Tracker: R9's slim explicit compare-select (min-tree + first-match r
    // + strict-< on j=sub). NO packed-fminf (R8 rule).
    float md[4];
    int   mc[4];
#pragma unroll
    for (int tt = 0; tt < 4; ++tt) { md[tt] = INFINITY; mc[tt] = 0; }

#pragma unroll 4
    for (int sub = 0; sub < 64; ++sub) {
        const unsigned char* rowb = lds + (sub * 16 + ln) * 128;
        // h = 0.5||c||^2: 4 distinct 16B lines per wave-instr, q-broadcast,
        // L1-hot (R2-proven global-read pattern).
        f32x4 h4 = *(const f32x4*)(hcn_k + sub * 16 + q4);
        f32x4 a[4];
#pragma unroll
        for (int tt = 0; tt < 4; ++tt) a[tt] = h4;
#pragma unroll
        for (int ks = 0; ks < 2; ++ks) {
            int cidx = ((ks * 4 + q) ^ (ln & 7)) * 16;
            bf16x8 ah = __builtin_bit_cast(bf16x8, *(const short8*)(rowb + cidx));
#pragma unroll
            for (int tt = 0; tt < 4; ++tt)
                a[tt] = __builtin_amdgcn_mfma_f32_16x16x32_bf16(
                    ah, __builtin_bit_cast(bf16x8, bh[tt][ks]), a[tt], 0, 0, 0);
        }
        const int j4 = sub * 4;
#pragma unroll
        for (int tt = 0; tt < 4; ++tt) {
            // Min-tree + first-match r (smallest r on ties), strict-< on sub
            // (earliest sub on ties) — identical lexicographic winner to R9.
            float m01 = fminf(a[tt][0], a[tt][1]);
            float m23 = fminf(a[tt][2], a[tt][3]);
            float m   = fminf(m01, m23);
            int rw = (m == a[tt][0]) ? 0 :
                     (m == a[tt][1]) ? 1 :
                     (m == a[tt][2]) ? 2 : 3;
            bool lt = m < md[tt];
            md[tt] = lt ? m : md[tt];
            mc[tt] = lt ? (j4 + rw) : mc[tt];
        }
    }

    // ---- Epilogue A: consensus + SSE + counts (registers only) ----
    double waveSse = 0.0;
    int c1s[4];
#pragma unroll
    for (int tt = 0; tt < 4; ++tt) {
        float d1 = md[tt];
        int   c1 = ((mc[tt] >> 2) << 4) + q4 + (mc[tt] & 3);   // sub*16+q4+r
        // Cross-lane top-1 merge over q (xor 16, 32), lexicographic ->
        // all 4 q-lanes converge bitwise on the same (d1, c1). (R9-proven.)
#pragma unroll
        for (int off = 16; off <= 32; off <<= 1) {
            float ov = __shfl_xor(d1, off);
            int   oc = __shfl_xor(c1, off);
            bool w = (ov < d1) || (ov == d1 && oc < c1);
            d1 = w ? ov : d1;
            c1 = w ? oc : c1;
        }
        c1s[tt] = c1;

        if (q == 0) {                        // one vote per query
            // ||x - c||^2 = ||x||^2 + 2*(0.5||c||^2 - x.c) = xn + 2*score
            waveSse += (double)(xn[tt] + 2.0f * d1);
            atomicAdd(&counts[k * C_ + c1], 1);
        }
    }

    // One fp64 atomic per wave.
    for (int off = 32; off > 0; off >>= 1) waveSse += __shfl_down(waveSse, off);
    if (lane == 0) atomicAdd(sse, waveSse);

    __syncthreads();   // all waves done reading the image -> safe to alias

    // ---- Epilogue B1: idx publish into aliased LDS (2 KB at image base) ----
    if (q == 0) {
#pragma unroll
        for (int tt = 0; tt < 4; ++tt)
            idxS[wave * 64 + tt * 16 + ln] = c1s[tt];   // idx for local t
    }
    __syncthreads();   // idx table visible to all waves

    // ---- Epilogue B2: coalesced quantized write (R7-proven pattern) ----
    // Wave owns 8 ch rows (ch = wave*8 + h*4 + rr) x 512 t, 2 segs of 256 t.
    // Lane l covers local t = seg*256 + 4l..4l+3: gather exact fp32 codebook
    // row-slices (L2-hot), register-transpose, dwordx4 stores (64 lanes x
    // 16 B = 1 KB contiguous per wave-instr -> full cache lines, no RMW).
    const float* cb_k = cb + (size_t)k * C_ * CH_;
#pragma unroll
    for (int seg = 0; seg < 2; ++seg) {
        const int L = seg * 256 + 4 * lane;
        i32x4 idx4 = *(const i32x4*)(idxS + L);
#pragma unroll
        for (int h = 0; h < 2; ++h) {
            f32x4 g[4];
#pragma unroll
            for (int m = 0; m < 4; ++m)
                g[m] = *(const f32x4*)(cb_k + (size_t)idx4[m] * CH_
                                       + wave * 8 + h * 4);
#pragma unroll
            for (int rr = 0; rr < 4; ++rr) {
                f32x4 v = { g[0][rr], g[1][rr], g[2][rr], g[3][rr] };
                *(f32x4*)(out + ((size_t)(b * D_ + k * CH_ + wave * 8 + h * 4
                                          + rr)) * T_ + t0b + L) = v;
            }
        }
    }
}

// ---------------------------------------------------------------------------
// Finalize: one block per k -> perplexity; block 0 also writes commit loss.
// ---------------------------------------------------------------------------
__global__ void vq_final(const int* __restrict__ counts,
                         const double* __restrict__ sse,
                         float* __restrict__ out) {
    __shared__ double part[4];
    const int tid = threadIdx.x;
    const int k   = blockIdx.x;
    double local = 0.0;
    for (int j = tid; j < C_; j += 256) {
        double p = (double)counts[k * C_ + j] * (1.0 / (double)(B_ * T_));
        local += -p * log(p + 1e-8);
    }
    for (int off = 32; off > 0; off >>= 1) local += __shfl_down(local, off);
    if ((tid & 63) == 0) part[tid >> 6] = local;
    __syncthreads();
    if (tid == 0) {
        double sum = part[0] + part[1] + part[2] + part[3];
        out[QOFF + 1 + k] = (float)exp(sum);
        if (k == 0)
            out[QOFF] = (float)(1.25 * (*sse) / (double)NEL_);
    }
}

// ---------------------------------------------------------------------------
extern "C" void kernel_launch(void* const* d_in, const int* in_sizes, int n_in,
                              void* d_out, int out_size, void* d_ws, size_t ws_size,
                              hipStream_t stream) {
    const float* x  = (const float*)d_in[0];
    const float* cb = (const float*)d_in[1];
    float* out = (float*)d_out;

    float*         hcn    = (float*)((char*)d_ws + WS_HCN);
    int*           counts = (int*)((char*)d_ws + WS_CNT);
    double*        sse    = (double*)((char*)d_ws + WS_SSE);
    unsigned char* cbS    = (unsigned char*)((char*)d_ws + WS_CBS);

    vq_prep<<<(K_ * C_ * 8) / 256, 256, 0, stream>>>(cb, cbS, hcn, counts, sse);
    vq_main<<<B_ * K_ * 4, 512, 0, stream>>>(x, cb, cbS, hcn, out, counts, sse);
    vq_final<<<K_, 256, 0, stream>>>(counts, sse, out);
}

// Round 11
// 196.500 us; speedup vs baseline: 1.0897x; 1.0897x over previous
//
#include <hip/hip_runtime.h>
#include <hip/hip_bf16.h>
#include <math.h>

// Problem constants
#define B_   16
#define D_   512
#define T_   2048
#define K_   8
#define C_   1024
#define CH_  64
#define NEL_ (B_ * D_ * T_)        // 16777216
#define QOFF 16777216              // out: [quantized | commit | ppl[8]]

// ws layout
#define WS_HCN   0                          // float[K*C]   32 KB (0.5*||c||^2)
#define WS_CNT   32768                      // int[K*C]     32 KB
#define WS_SSE   65536                      // double       8 B
#define WS_CBS   66048                      // swizzled bf16 (hi only) image, 8192 rows * 128 B = 1 MB
// image: row r (= k*1024+c) at WS_CBS + r*128; 16B group s (s=0..7, ch 8s..8s+7,
// negated bf16) stored at ((s ^ (r & 7)) * 16).

typedef __attribute__((ext_vector_type(8))) short   short8;
typedef __attribute__((ext_vector_type(8))) __bf16  bf16x8;
typedef __attribute__((ext_vector_type(4))) float   f32x4;
typedef __attribute__((ext_vector_type(4))) int     i32x4;

__device__ __forceinline__ unsigned short f2bf_rne(float f) {
    unsigned u = __builtin_bit_cast(unsigned, f);
    u = u + 0x7FFFu + ((u >> 16) & 1u);
    return (unsigned short)(u >> 16);
}

__device__ __forceinline__ void gload_lds16(const void* gsrc, void* ldst) {
    __builtin_amdgcn_global_load_lds(
        (const __attribute__((address_space(1))) unsigned int*)gsrc,
        (__attribute__((address_space(3))) unsigned int*)ldst,
        16, 0, 0);
}

// ---------------------------------------------------------------------------
// Prep (R0/R2-proven): swizzled bf16 (hi-only) image of (-c) + 0.5*||c||^2,
// plus counts/sse zero-init. One thread per 16B group. 65536 threads.
// ---------------------------------------------------------------------------
__global__ void vq_prep(const float* __restrict__ cb,
                        unsigned char* __restrict__ cbS,
                        float* __restrict__ hcn,
                        int* __restrict__ counts,
                        double* __restrict__ sse) {
    int g   = blockIdx.x * 256 + threadIdx.x;
    if (g < K_ * C_) counts[g] = 0;
    if (g == 0) *sse = 0.0;

    int row = g >> 3;
    int s8  = g & 7;
    const float* src = cb + (size_t)row * CH_;

    short8 val;
#pragma unroll
    for (int j = 0; j < 8; ++j)
        val[j] = (short)f2bf_rne(-src[s8 * 8 + j]);
    *(short8*)(cbS + (size_t)row * 128 + ((s8 ^ (row & 7)) * 16)) = val;

    if (s8 == 0) {
        float s = 0.f;
#pragma unroll 8
        for (int ch = 0; ch < CH_; ++ch) {
            float v = src[ch];
            s = fmaf(v, v, s);
        }
        hcn[row] = 0.5f * s;
    }
}

// ---------------------------------------------------------------------------
// Main — R6's geometry revived with R9's proven tracker.
// R10 post-mortem: barrier-free at 8 waves/CU LOST to R9's 16 waves/CU
// (occupancy was binding, 142 vs 108 µs). R8 control proved packed-fminf
// (not LDS size / thread count) caused every prior failure; R10 proved
// 128 KB static + 512 threads launches. This kernel gets BOTH levers:
//   - 512 threads, 64 KB LDS -> 2 blocks/CU = 16 waves/CU (R9 occupancy)
//   - 4 chunks x 256 codes, double-buffered -> 5 barriers per 512 t
//     (R9: 10 per 256 t = 4x more drains per unit work); the two resident
//     blocks' drain phases interleave.
// Launch config bracketed by proven points: 512t @ 37.9 KB (R1) and
// 512t @ 131 KB (R10). Tracker: R9's slim explicit compare-select VERBATIM
// (no packed-fminf); j = chunk*16+sub in [0,64) -> identical lexicographic
// winner; absmax must reproduce 0.6113281 bit-for-bit.
//
// Block = 512 (8 waves), wave owns 64 t = 4 t-tiles (R9 register shape).
// Grid = 512 = B*K*4 t-quarters, exactly 2 blocks/CU, 1 round.
// hcn from global (R2/R10-proven broadcast); idxS aliases buf0 post-sweep
// (chunk 3 reads buf1; buf0 quiescent after the chunk-3 barrier).
// Epilogue: R10's coalesced 1KB dwordx4 out-writes verbatim.
// ---------------------------------------------------------------------------
#define LDSBUF 32768

__global__ __launch_bounds__(512, 2) void vq_main(
    const float* __restrict__ x,
    const float* __restrict__ cb,
    const unsigned char* __restrict__ cbS,
    const float* __restrict__ hcn,
    float* __restrict__ out,
    int* __restrict__ counts,
    double* __restrict__ sse)
{
    __shared__ __align__(16) unsigned char lds[2 * LDSBUF];  // 65536 B
    int* idxS = (int*)lds;              // alias; valid after post-sweep barrier

    const int tid  = threadIdx.x;
    const int lane = tid & 63;
    const int wave = tid >> 6;          // 0..7
    const int ln   = lane & 15;
    const int q    = lane >> 4;
    const int q4   = q * 4;

    const int bid = blockIdx.x;
    const int tq  = bid & 3;            // quarter of T
    const int k   = (bid >> 2) & 7;
    const int b   = bid >> 5;
    const int t0b = tq * 512;           // block's t base (512 t)
    const int tw  = t0b + wave * 64;    // wave's t base  (64 t)

    const unsigned char* cbS_k = cbS + (size_t)k * C_ * 128;
    const float*         hcn_k = hcn + k * C_;

    // ---- Stage chunk 0 (256 codes, 32 KB) into buf0: 4 x 16 B per thread.
    // dst = lds + tid*16 (+ i*8192): wave-uniform base + lane*16 — matches
    // gload_lds lane mapping (R2/R10-proven).
    {
        const unsigned char* src = cbS_k + tid * 16;
        unsigned char*       dst = lds   + tid * 16;
#pragma unroll
        for (int i = 0; i < 4; ++i)
            gload_lds16(src + i * 8192, dst + i * 8192);
    }

    // ---- x fragments (queries) + ||x||^2 per query (R9 verbatim) ----
    // Overlaps the in-flight chunk-0 staging.
    short8 bh[4][2];    // [tt][kstep]
    float  xn[4];       // ||x_t||^2 for t = tw + tt*16 + ln (all lanes)
#pragma unroll
    for (int tt = 0; tt < 4; ++tt) {
        int t = tw + tt * 16 + ln;
        float pn = 0.f;
#pragma unroll
        for (int ks = 0; ks < 2; ++ks) {
            const float* xp = x + ((size_t)(b * D_ + k * CH_ + ks * 32 + q * 8)) * T_ + t;
            short8 sh;
#pragma unroll
            for (int j = 0; j < 8; ++j) {
                float v = xp[(size_t)j * T_];
                pn = fmaf(v, v, pn);
                sh[j] = (short)f2bf_rne(v);
            }
            bh[tt][ks] = sh;
        }
        pn += __shfl_xor(pn, 16);       // sum the 4 q-lane partials
        pn += __shfl_xor(pn, 32);
        xn[tt] = pn;
    }

    // ---- Sweep: 4 chunks of 256 codes, double-buffered ----
    // Tracker: R9's slim explicit compare-select. j = chunk*16+sub in [0,64).
    float md[4];
    int   mc[4];
#pragma unroll
    for (int tt = 0; tt < 4; ++tt) { md[tt] = INFINITY; mc[tt] = 0; }

    for (int chunk = 0; chunk < 4; ++chunk) {
        __syncthreads();   // drains this chunk's async loads

        if (chunk < 3) {   // prefetch next chunk into the other buffer
            const unsigned char* src =
                cbS_k + (size_t)(chunk + 1) * 32768 + tid * 16;
            unsigned char* dst = lds + ((chunk + 1) & 1) * LDSBUF + tid * 16;
#pragma unroll
            for (int i = 0; i < 4; ++i)
                gload_lds16(src + i * 8192, dst + i * 8192);
        }

        const unsigned char* buf = lds + (chunk & 1) * LDSBUF;
#pragma unroll 4
        for (int sub = 0; sub < 16; ++sub) {
            const unsigned char* rowb = buf + (sub * 16 + ln) * 128;
            // h = 0.5||c||^2: q-broadcast 16B lines, L1-hot (R2/R10-proven).
            f32x4 h4 = *(const f32x4*)(hcn_k + chunk * 256 + sub * 16 + q4);
            f32x4 a[4];
#pragma unroll
            for (int tt = 0; tt < 4; ++tt) a[tt] = h4;
#pragma unroll
            for (int ks = 0; ks < 2; ++ks) {
                int cidx = ((ks * 4 + q) ^ (ln & 7)) * 16;
                bf16x8 ah = __builtin_bit_cast(bf16x8, *(const short8*)(rowb + cidx));
#pragma unroll
                for (int tt = 0; tt < 4; ++tt)
                    a[tt] = __builtin_amdgcn_mfma_f32_16x16x32_bf16(
                        ah, __builtin_bit_cast(bf16x8, bh[tt][ks]), a[tt], 0, 0, 0);
            }
            const int j4 = (chunk * 16 + sub) * 4;
#pragma unroll
            for (int tt = 0; tt < 4; ++tt) {
                // Min-tree + first-match r (smallest r on ties), strict-< on
                // j (earliest j on ties) — identical winner to R9.
                float m01 = fminf(a[tt][0], a[tt][1]);
                float m23 = fminf(a[tt][2], a[tt][3]);
                float m   = fminf(m01, m23);
                int rw = (m == a[tt][0]) ? 0 :
                         (m == a[tt][1]) ? 1 :
                         (m == a[tt][2]) ? 2 : 3;
                bool lt = m < md[tt];
                md[tt] = lt ? m : md[tt];
                mc[tt] = lt ? (j4 + rw) : mc[tt];
            }
        }
    }

    // ---- Epilogue A: consensus + SSE + counts (registers only) ----
    double waveSse = 0.0;
    int c1s[4];
#pragma unroll
    for (int tt = 0; tt < 4; ++tt) {
        float d1 = md[tt];
        int   c1 = ((mc[tt] >> 2) << 4) + q4 + (mc[tt] & 3);   // j*16+q4+r
        // Cross-lane top-1 merge over q (xor 16, 32), lexicographic ->
        // all 4 q-lanes converge bitwise on the same (d1, c1). (R9-proven.)
#pragma unroll
        for (int off = 16; off <= 32; off <<= 1) {
            float ov = __shfl_xor(d1, off);
            int   oc = __shfl_xor(c1, off);
            bool w = (ov < d1) || (ov == d1 && oc < c1);
            d1 = w ? ov : d1;
            c1 = w ? oc : c1;
        }
        c1s[tt] = c1;

        if (q == 0) {                        // one vote per query
            // ||x - c||^2 = ||x||^2 + 2*(0.5||c||^2 - x.c) = xn + 2*score
            waveSse += (double)(xn[tt] + 2.0f * d1);
            atomicAdd(&counts[k * C_ + c1], 1);
        }
    }

    // One fp64 atomic per wave.
    for (int off = 32; off > 0; off >>= 1) waveSse += __shfl_down(waveSse, off);
    if (lane == 0) atomicAdd(sse, waveSse);

    // idx publish into buf0 (quiescent: chunk 3 read buf1; all waves passed
    // the chunk-3 barrier before writing here).
    if (q == 0) {
#pragma unroll
        for (int tt = 0; tt < 4; ++tt)
            idxS[wave * 64 + tt * 16 + ln] = c1s[tt];   // idx for local t
    }
    __syncthreads();   // idx table visible to all waves

    // ---- Epilogue B: coalesced quantized write (R10 verbatim) ----
    // Wave owns 8 ch rows (ch = wave*8 + h*4 + rr) x 512 t, 2 segs of 256 t.
    // Lane l covers local t = seg*256 + 4l..4l+3: gather exact fp32 codebook
    // row-slices (L2-hot), register-transpose, dwordx4 stores (64 lanes x
    // 16 B = 1 KB contiguous per wave-instr -> full cache lines, no RMW).
    const float* cb_k = cb + (size_t)k * C_ * CH_;
#pragma unroll
    for (int seg = 0; seg < 2; ++seg) {
        const int L = seg * 256 + 4 * lane;
        i32x4 idx4 = *(const i32x4*)(idxS + L);
#pragma unroll
        for (int h = 0; h < 2; ++h) {
            f32x4 g[4];
#pragma unroll
            for (int m = 0; m < 4; ++m)
                g[m] = *(const f32x4*)(cb_k + (size_t)idx4[m] * CH_
                                       + wave * 8 + h * 4);
#pragma unroll
            for (int rr = 0; rr < 4; ++rr) {
                f32x4 v = { g[0][rr], g[1][rr], g[2][rr], g[3][rr] };
                *(f32x4*)(out + ((size_t)(b * D_ + k * CH_ + wave * 8 + h * 4
                                          + rr)) * T_ + t0b + L) = v;
            }
        }
    }
}

// ---------------------------------------------------------------------------
// Finalize: one block per k -> perplexity; block 0 also writes commit loss.
// ---------------------------------------------------------------------------
__global__ void vq_final(const int* __restrict__ counts,
                         const double* __restrict__ sse,
                         float* __restrict__ out) {
    __shared__ double part[4];
    const int tid = threadIdx.x;
    const int k   = blockIdx.x;
    double local = 0.0;
    for (int j = tid; j < C_; j += 256) {
        double p = (double)counts[k * C_ + j] * (1.0 / (double)(B_ * T_));
        local += -p * log(p + 1e-8);
    }
    for (int off = 32; off > 0; off >>= 1) local += __shfl_down(local, off);
    if ((tid & 63) == 0) part[tid >> 6] = local;
    __syncthreads();
    if (tid == 0) {
        double sum = part[0] + part[1] + part[2] + part[3];
        out[QOFF + 1 + k] = (float)exp(sum);
        if (k == 0)
            out[QOFF] = (float)(1.25 * (*sse) / (double)NEL_);
    }
}

// ---------------------------------------------------------------------------
extern "C" void kernel_launch(void* const* d_in, const int* in_sizes, int n_in,
                              void* d_out, int out_size, void* d_ws, size_t ws_size,
                              hipStream_t stream) {
    const float* x  = (const float*)d_in[0];
    const float* cb = (const float*)d_in[1];
    float* out = (float*)d_out;

    float*         hcn    = (float*)((char*)d_ws + WS_HCN);
    int*           counts = (int*)((char*)d_ws + WS_CNT);
    double*        sse    = (double*)((char*)d_ws + WS_SSE);
    unsigned char* cbS    = (unsigned char*)((char*)d_ws + WS_CBS);

    vq_prep<<<(K_ * C_ * 8) / 256, 256, 0, stream>>>(cb, cbS, hcn, counts, sse);
    vq_main<<<B_ * K_ * 4, 512, 0, stream>>>(x, cb, cbS, hcn, out, counts, sse);
    vq_final<<<K_, 256, 0, stream>>>(counts, sse, out);
}